// Round 6
// baseline (658.702 us; speedup 1.0000x reference)
//
#include <hip/hip_runtime.h>

#define BN_EPS 1e-5f

__device__ __forceinline__ float lrelu(float x){ return x > 0.f ? x : 0.2f*x; }

struct F3 { float x, y, z; };   // 12B, align 4 -> dwordx3-able

// ---------------- CSR build (dst-sorted edge list) ----------------

__global__ __launch_bounds__(256) void hist_k(const int* __restrict__ dst,
                                              int* __restrict__ deg, int E){
  int e = blockIdx.x*256 + threadIdx.x;
  if (e < E) atomicAdd(&deg[dst[e]], 1);
}

__global__ __launch_bounds__(256) void scan1_k(int* __restrict__ degoff,
                                               int* __restrict__ bsum, int N){
  __shared__ int s[256];
  int t = threadIdx.x, i = blockIdx.x*256 + t;
  int v = (i < N) ? degoff[i] : 0;
  s[t] = v; __syncthreads();
  int x = v;
  for (int d = 1; d < 256; d <<= 1){
    int y = (t >= d) ? s[t-d] : 0;
    __syncthreads();
    x += y; s[t] = x;
    __syncthreads();
  }
  if (i < N) degoff[i] = x - v;          // block-local exclusive
  if (t == 255) bsum[blockIdx.x] = x;    // block total
}

__global__ __launch_bounds__(256) void scan2_k(int* __restrict__ bsum, int nb){
  __shared__ int s[256];
  int t = threadIdx.x;
  int v = (t < nb) ? bsum[t] : 0;
  s[t] = v; __syncthreads();
  int x = v;
  for (int d = 1; d < 256; d <<= 1){
    int y = (t >= d) ? s[t-d] : 0;
    __syncthreads();
    x += y; s[t] = x;
    __syncthreads();
  }
  if (t < nb) bsum[t] = x - v;           // exclusive block offsets
}

__global__ __launch_bounds__(256) void scan3_k(int* __restrict__ off,
                                               int* __restrict__ cursor,
                                               const int* __restrict__ bsum,
                                               int N, int E){
  int i = blockIdx.x*256 + threadIdx.x;
  if (i < N){
    int o = off[i] + bsum[blockIdx.x];
    off[i] = o; cursor[i] = o;
  }
  if (i == 0) off[N] = E;
}

__global__ __launch_bounds__(256) void scatter_k(const int* __restrict__ src,
                                                 const int* __restrict__ dst,
                                                 int* __restrict__ cursor,
                                                 int* __restrict__ srcs, int E){
  int e = blockIdx.x*256 + threadIdx.x;
  if (e < E){
    int p = atomicAdd(&cursor[dst[e]], 1);
    srcs[p] = src[e];
  }
}

// ------------- fused GIN layer: CSR gather-agg -> GEMM1 -> BN -> GEMM2 --------
// 512 thr / 8 waves. Phase 0: 16x 32-lane groups aggregate 4 nodes each,
// lane ln owns features 3ln..3ln+2 (one dwordx3 per edge), accumulate in regs,
// deposit into hT (conflict-free: bank 9ln+3s+n, gcd(9,32)=1).
// Phases 1-3 = wave-uniform weight slices: wave w owns dims d0=w*12; W rows
// via s_load (uniform addr); per k-iter: 1 ds_read_b32 + 12 v_fmac.
__global__ __launch_bounds__(512) void mlp_fused_k(
    const float* __restrict__ hin, float* __restrict__ hout,
    const int* __restrict__ off, const int* __restrict__ srcs,
    const float* __restrict__ W1, const float* __restrict__ b1,
    const float* __restrict__ g, const float* __restrict__ beta,
    const float* __restrict__ mean, const float* __restrict__ var,
    const float* __restrict__ W2, const float* __restrict__ b2, int N)
{
  __shared__ float hT[96*67];          // [k][n] pad 67
  int t = threadIdx.x;
  int nbase = blockIdx.x * 64;

  // ---- phase 0: gather-aggregate into hT ----
  {
    int grp = t >> 5, ln = t & 31;     // 16 groups, lane owns feats 3ln..3ln+2
    for (int n = grp; n < 64; n += 16){
      int node = nbase + n;
      if (node >= N) break;            // tail: junk columns never stored
      const char* selfp = (const char*)hin + (size_t)node*384 + ln*12;
      F3 a = *(const F3*)selfp;
      int jb = off[node], je = off[node+1];
      for (int j = jb; j < je; ++j){
        const char* qp = (const char*)hin + (size_t)srcs[j]*384 + ln*12;
        F3 q = *(const F3*)qp;
        a.x += q.x; a.y += q.y; a.z += q.z;
      }
      hT[(3*ln+0)*67 + n] = a.x;
      hT[(3*ln+1)*67 + n] = a.y;
      hT[(3*ln+2)*67 + n] = a.z;
    }
  }
  __syncthreads();

  // ---- phase 1: GEMM1 ----
  int ln = t & 63;
  int d0 = __builtin_amdgcn_readfirstlane((t >> 6) * 12);  // wave-uniform dims

  float acc[12];
  #pragma unroll
  for (int j = 0; j < 12; ++j) acc[j] = b1[d0+j];
  #pragma unroll 4
  for (int k = 0; k < 96; ++k){
    float hk = hT[k*67 + ln];
    const float* wr = W1 + k*96 + d0;  // uniform address -> s_load
    #pragma unroll
    for (int j = 0; j < 12; ++j) acc[j] = fmaf(hk, wr[j], acc[j]);
  }
  __syncthreads();                     // all GEMM1 reads done before overwrite

  // ---- phase 2: mid = bn(lrelu(acc)) back into hT ----
  #pragma unroll
  for (int j = 0; j < 12; ++j){
    int d = d0 + j;
    float s = g[d] * rsqrtf(var[d] + BN_EPS);
    float m = lrelu(acc[j]);
    hT[d*67 + ln] = (m - mean[d])*s + beta[d];
  }
  __syncthreads();

  // ---- phase 3: GEMM2 ----
  #pragma unroll
  for (int j = 0; j < 12; ++j) acc[j] = b2[d0+j];
  #pragma unroll 4
  for (int k = 0; k < 96; ++k){
    float hk = hT[k*67 + ln];
    const float* wr = W2 + k*96 + d0;
    #pragma unroll
    for (int j = 0; j < 12; ++j) acc[j] = fmaf(hk, wr[j], acc[j]);
  }
  __syncthreads();                     // all GEMM2 reads done before overwrite

  #pragma unroll
  for (int j = 0; j < 12; ++j)
    hT[(d0+j)*67 + ln] = lrelu(acc[j]);
  __syncthreads();

  // ---- store tile, coalesced ----
  int lim = (N - nbase) * 96;
  float* obase = hout + (size_t)nbase*96;
  #pragma unroll
  for (int i = 0; i < 12; ++i){
    int tid = t + 512*i;
    int n = tid / 96, k = tid - n*96;
    if (tid < lim) obase[tid] = hT[k*67 + n];
  }
}

// ---------------- pooling over sorted batch ----------------

__global__ __launch_bounds__(256) void bounds_k(const int* __restrict__ batch,
                                                int* __restrict__ go, int N, int G){
  int i = blockIdx.x*256 + threadIdx.x;
  if (i >= N) return;
  int b = batch[i];
  int prev = (i == 0) ? -1 : batch[i-1];
  for (int g = prev+1; g <= b; ++g) go[g] = i;
  if (i == N-1){
    for (int g = b+1; g <= G; ++g) go[g] = N;
  }
}

__global__ __launch_bounds__(128) void pool_k(const float* __restrict__ h,
                                              const int* __restrict__ go,
                                              float* __restrict__ pooled){
  int g = blockIdx.x, d = threadIdx.x;
  if (d >= 96) return;
  int nb = go[g], ne = go[g+1];
  float acc = 0.f;
  for (int n = nb; n < ne; ++n) acc += h[(size_t)n*96 + d];
  pooled[g*96 + d] = acc;
}

// ---------------- cond MLP + concat + BN + fc ----------------

__global__ __launch_bounds__(64) void final_k(
    const float* __restrict__ cond, const float* __restrict__ pooled,
    const float* __restrict__ cW1, const float* __restrict__ cb1,
    const float* __restrict__ cg, const float* __restrict__ cbeta,
    const float* __restrict__ cmean, const float* __restrict__ cvar,
    const float* __restrict__ cW2, const float* __restrict__ cb2,
    const float* __restrict__ bn_g, const float* __restrict__ bn_b,
    const float* __restrict__ bn_mean, const float* __restrict__ bn_var,
    const float* __restrict__ fcW, const float* __restrict__ fcb,
    float* __restrict__ out)
{
  int g = blockIdx.x, t = threadIdx.x;
  float cin[7];
  #pragma unroll
  for (int j = 0; j < 7; ++j) cin[j] = cond[g*7+j];
  float c1[5];
  #pragma unroll
  for (int i = 0; i < 5; ++i){
    float a = cb1[i];
    #pragma unroll
    for (int j = 0; j < 7; ++j) a = fmaf(cin[j], cW1[j*5+i], a);
    float s = cg[i] * rsqrtf(cvar[i] + BN_EPS);
    a = (a - cmean[i])*s + cbeta[i];
    c1[i] = a > 0.f ? a : 0.f;
  }
  float c2[5];
  #pragma unroll
  for (int i = 0; i < 5; ++i){
    float a = cb2[i];
    #pragma unroll
    for (int j = 0; j < 5; ++j) a = fmaf(c1[j], cW2[j*5+i], a);
    c2[i] = a > 0.f ? a : 0.f;
  }
  float acc = fcb[t];
  #pragma unroll
  for (int j = 0; j < 5; ++j){
    float s = bn_g[j] * rsqrtf(bn_var[j] + BN_EPS);
    float nb = (c2[j] - bn_mean[j])*s + bn_b[j];
    acc = fmaf(nb, fcW[j*64 + t], acc);
  }
  for (int j = 5; j < 101; ++j){
    float vj = pooled[g*96 + (j-5)];
    float s = bn_g[j] * rsqrtf(bn_var[j] + BN_EPS);
    float nb = (vj - bn_mean[j])*s + bn_b[j];
    acc = fmaf(nb, fcW[j*64 + t], acc);
  }
  out[g*64 + t] = acc;
}

// ---------------- launch ----------------

extern "C" void kernel_launch(void* const* d_in, const int* in_sizes, int n_in,
                              void* d_out, int out_size, void* d_ws, size_t ws_size,
                              hipStream_t stream)
{
  const float* x         = (const float*)d_in[0];
  const float* cond      = (const float*)d_in[1];
  const int*   ei        = (const int*)  d_in[2];
  const int*   batch     = (const int*)  d_in[3];
  const float* conv_W1   = (const float*)d_in[4];
  const float* conv_b1   = (const float*)d_in[5];
  const float* conv_g    = (const float*)d_in[6];
  const float* conv_beta = (const float*)d_in[7];
  const float* conv_mean = (const float*)d_in[8];
  const float* conv_var  = (const float*)d_in[9];
  const float* conv_W2   = (const float*)d_in[10];
  const float* conv_b2   = (const float*)d_in[11];
  const float* cW1       = (const float*)d_in[12];
  const float* cb1       = (const float*)d_in[13];
  const float* cg        = (const float*)d_in[14];
  const float* cbeta     = (const float*)d_in[15];
  const float* cmean     = (const float*)d_in[16];
  const float* cvar      = (const float*)d_in[17];
  const float* cW2       = (const float*)d_in[18];
  const float* cb2       = (const float*)d_in[19];
  const float* bn_g      = (const float*)d_in[20];
  const float* bn_b      = (const float*)d_in[21];
  const float* bn_mean   = (const float*)d_in[22];
  const float* bn_var    = (const float*)d_in[23];
  const float* fc_W      = (const float*)d_in[24];
  const float* fc_b      = (const float*)d_in[25];

  const int D = 96;
  int N = in_sizes[0] / D;
  int G = in_sizes[1] / 7;
  int E = in_sizes[2] / 2;
  const int* src = ei;
  const int* dst = ei + E;

  char* p = (char*)d_ws;
  auto carve = [&](size_t bytes)->void*{
    void* r = (void*)p; p += (bytes + 255) & ~(size_t)255; return r;
  };
  int*   off    = (int*)  carve((size_t)(N+1)*4);
  int*   cursor = (int*)  carve((size_t)N*4);
  int*   bsum   = (int*)  carve(256*4);
  int*   srcs   = (int*)  carve((size_t)E*4);
  int*   go     = (int*)  carve((size_t)(G+1)*4);
  float* pooled = (float*)carve((size_t)G*D*4);
  float* hA     = (float*)carve((size_t)N*D*4);
  float* hB     = (float*)carve((size_t)N*D*4);

  int gE = (E+255)/256, gN = (N+255)/256;

  hipMemsetAsync(off, 0, (size_t)(N+1)*4, stream);
  hist_k   <<<gE, 256, 0, stream>>>(dst, off, E);
  scan1_k  <<<gN, 256, 0, stream>>>(off, bsum, N);
  scan2_k  <<<1,  256, 0, stream>>>(bsum, gN);
  scan3_k  <<<gN, 256, 0, stream>>>(off, cursor, bsum, N, E);
  scatter_k<<<gE, 256, 0, stream>>>(src, dst, cursor, srcs, E);
  bounds_k <<<gN, 256, 0, stream>>>(batch, go, N, G);

  // ping-pong: gather reads random rows of the PREVIOUS buffer -> no in-place
  const float* hin = x;
  float* houts[3] = { hA, hB, hA };
  int nblk = (N+63)/64;
  for (int l = 0; l < 3; ++l){
    mlp_fused_k<<<nblk, 512, 0, stream>>>(hin, houts[l], off, srcs,
        conv_W1 + (size_t)l*D*D, conv_b1 + l*D,
        conv_g + l*D, conv_beta + l*D, conv_mean + l*D, conv_var + l*D,
        conv_W2 + (size_t)l*D*D, conv_b2 + l*D, N);
    hin = houts[l];
  }

  pool_k <<<G, 128, 0, stream>>>(hA, go, pooled);
  final_k<<<G, 64,  0, stream>>>(cond, pooled, cW1, cb1, cg, cbeta, cmean, cvar,
                                 cW2, cb2, bn_g, bn_b, bn_mean, bn_var,
                                 fc_W, fc_b, (float*)d_out);
}

// Round 7
// 486.568 us; speedup vs baseline: 1.3538x; 1.3538x over previous
//
#include <hip/hip_runtime.h>

#define BN_EPS 1e-5f

__device__ __forceinline__ float lrelu(float x){ return x > 0.f ? x : 0.2f*x; }

struct F3 { float x, y, z; };   // 12B -> global_load_dwordx3

// ---------------- CSR build (dst-sorted edge list) ----------------

__global__ __launch_bounds__(256) void hist_k(const int* __restrict__ dst,
                                              int* __restrict__ deg, int E){
  int e = blockIdx.x*256 + threadIdx.x;
  if (e < E) atomicAdd(&deg[dst[e]], 1);
}

__global__ __launch_bounds__(256) void scan1_k(int* __restrict__ degoff,
                                               int* __restrict__ bsum, int N){
  __shared__ int s[256];
  int t = threadIdx.x, i = blockIdx.x*256 + t;
  int v = (i < N) ? degoff[i] : 0;
  s[t] = v; __syncthreads();
  int x = v;
  for (int d = 1; d < 256; d <<= 1){
    int y = (t >= d) ? s[t-d] : 0;
    __syncthreads();
    x += y; s[t] = x;
    __syncthreads();
  }
  if (i < N) degoff[i] = x - v;          // block-local exclusive
  if (t == 255) bsum[blockIdx.x] = x;    // block total
}

__global__ __launch_bounds__(256) void scan2_k(int* __restrict__ bsum, int nb){
  __shared__ int s[256];
  int t = threadIdx.x;
  int v = (t < nb) ? bsum[t] : 0;
  s[t] = v; __syncthreads();
  int x = v;
  for (int d = 1; d < 256; d <<= 1){
    int y = (t >= d) ? s[t-d] : 0;
    __syncthreads();
    x += y; s[t] = x;
    __syncthreads();
  }
  if (t < nb) bsum[t] = x - v;           // exclusive block offsets
}

__global__ __launch_bounds__(256) void scan3_k(int* __restrict__ off,
                                               int* __restrict__ cursor,
                                               const int* __restrict__ bsum,
                                               int N, int E){
  int i = blockIdx.x*256 + threadIdx.x;
  if (i < N){
    int o = off[i] + bsum[blockIdx.x];
    off[i] = o; cursor[i] = o;
  }
  if (i == 0) off[N] = E;
}

__global__ __launch_bounds__(256) void scatter_k(const int* __restrict__ src,
                                                 const int* __restrict__ dst,
                                                 int* __restrict__ cursor,
                                                 int* __restrict__ srcs, int E){
  int e = blockIdx.x*256 + threadIdx.x;
  if (e < E){
    int p = atomicAdd(&cursor[dst[e]], 1);
    srcs[p] = src[e];
  }
}

// ---------------- GIN aggregation: lane owns feats 3ln..3ln+2 -----------------
// One dwordx3 per edge per lane; 2-deep unroll -> two independent load chains.
__global__ __launch_bounds__(256) void agg_k(const float* __restrict__ hin,
                                             float* __restrict__ hout,
                                             const int* __restrict__ off,
                                             const int* __restrict__ srcs, int N){
  int node = blockIdx.x*8 + (threadIdx.x >> 5);
  int ln = threadIdx.x & 31;
  if (node >= N) return;
  F3 a = *((const F3*)(hin + (size_t)node*96) + ln);
  float bx = 0.f, by = 0.f, bz = 0.f;
  int jb = off[node], je = off[node+1];
  int j = jb;
  for (; j+1 < je; j += 2){
    int s0 = srcs[j], s1 = srcs[j+1];
    F3 q0 = *((const F3*)(hin + (size_t)s0*96) + ln);
    F3 q1 = *((const F3*)(hin + (size_t)s1*96) + ln);
    a.x += q0.x; a.y += q0.y; a.z += q0.z;
    bx  += q1.x; by  += q1.y; bz  += q1.z;
  }
  if (j < je){
    int s0 = srcs[j];
    F3 q0 = *((const F3*)(hin + (size_t)s0*96) + ln);
    a.x += q0.x; a.y += q0.y; a.z += q0.z;
  }
  a.x += bx; a.y += by; a.z += bz;
  *((F3*)(hout + (size_t)node*96) + ln) = a;
}

// ---------------- fused MLP: wave-uniform weight slices -----------------------
// 256 thr / 4 waves; wave w owns dims d0=w*24 (uniform -> W via s_load);
// lane = node (64-node tile). Per k-iter: 1 ds_read_b32 + 24 v_fmac.
__global__ __launch_bounds__(256) void mlp_sw_k(
    const float* __restrict__ hin, float* __restrict__ hout,
    const float* __restrict__ W1, const float* __restrict__ b1,
    const float* __restrict__ g, const float* __restrict__ beta,
    const float* __restrict__ mean, const float* __restrict__ var,
    const float* __restrict__ W2, const float* __restrict__ b2, int N)
{
  __shared__ float hT[96*67];          // [k][n] pad 67 (bank stride 3, coprime 32)
  int t = threadIdx.x;
  int nbase = blockIdx.x * 64;
  int lim = (N - nbase) * 96;
  const float* hbase = hin + (size_t)nbase*96;

  #pragma unroll
  for (int i = 0; i < 24; ++i){        // coalesced stage-in, transpose in LDS
    int tid = t + 256*i;
    float v = (tid < lim) ? hbase[tid] : 0.f;
    int n = tid / 96, k = tid - n*96;
    hT[k*67 + n] = v;
  }
  __syncthreads();

  int ln = t & 63;
  int d0 = __builtin_amdgcn_readfirstlane((t >> 6) * 24);  // wave-uniform dims

  float acc[24];
  #pragma unroll
  for (int j = 0; j < 24; ++j) acc[j] = b1[d0+j];
  #pragma unroll 2
  for (int k = 0; k < 96; ++k){
    float hk = hT[k*67 + ln];
    const float* wr = W1 + k*96 + d0;  // uniform address -> s_load
    #pragma unroll
    for (int j = 0; j < 24; ++j) acc[j] = fmaf(hk, wr[j], acc[j]);
  }
  __syncthreads();                     // all GEMM1 reads done before overwrite

  #pragma unroll
  for (int j = 0; j < 24; ++j){        // mid = bn(lrelu(acc)) -> hT rows d0..
    int d = d0 + j;
    float s = g[d] * rsqrtf(var[d] + BN_EPS);
    float m = lrelu(acc[j]);
    hT[d*67 + ln] = (m - mean[d])*s + beta[d];
  }
  __syncthreads();

  #pragma unroll
  for (int j = 0; j < 24; ++j) acc[j] = b2[d0+j];
  #pragma unroll 2
  for (int k = 0; k < 96; ++k){
    float hk = hT[k*67 + ln];
    const float* wr = W2 + k*96 + d0;
    #pragma unroll
    for (int j = 0; j < 24; ++j) acc[j] = fmaf(hk, wr[j], acc[j]);
  }
  __syncthreads();                     // all GEMM2 reads done before overwrite

  #pragma unroll
  for (int j = 0; j < 24; ++j)
    hT[(d0+j)*67 + ln] = lrelu(acc[j]);
  __syncthreads();

  float* obase = hout + (size_t)nbase*96;
  #pragma unroll
  for (int i = 0; i < 24; ++i){        // transpose out, coalesced global write
    int tid = t + 256*i;
    int n = tid / 96, k = tid - n*96;
    if (tid < lim) obase[tid] = hT[k*67 + n];
  }
}

// ---------------- pooling over sorted batch ----------------

__global__ __launch_bounds__(256) void bounds_k(const int* __restrict__ batch,
                                                int* __restrict__ go, int N, int G){
  int i = blockIdx.x*256 + threadIdx.x;
  if (i >= N) return;
  int b = batch[i];
  int prev = (i == 0) ? -1 : batch[i-1];
  for (int g = prev+1; g <= b; ++g) go[g] = i;
  if (i == N-1){
    for (int g = b+1; g <= G; ++g) go[g] = N;
  }
}

// ---------------- fused pool + cond MLP + concat + BN + fc --------------------
// block = group g; 384 thr = 4 parallel row streams of 96 lanes each.
__global__ __launch_bounds__(384) void poolfinal_k(
    const float* __restrict__ h, const int* __restrict__ go,
    const float* __restrict__ cond,
    const float* __restrict__ cW1, const float* __restrict__ cb1,
    const float* __restrict__ cg, const float* __restrict__ cbeta,
    const float* __restrict__ cmean, const float* __restrict__ cvar,
    const float* __restrict__ cW2, const float* __restrict__ cb2,
    const float* __restrict__ bn_g, const float* __restrict__ bn_b,
    const float* __restrict__ bn_mean, const float* __restrict__ bn_var,
    const float* __restrict__ fcW, const float* __restrict__ fcb,
    float* __restrict__ out)
{
  __shared__ float ps[4][96];
  __shared__ float pl[96];
  int g = blockIdx.x, t = threadIdx.x;
  int s = t / 96, d = t - s*96;        // s in 0..3
  {
    float acc = 0.f;
    int nb = go[g], ne = go[g+1];
    for (int n = nb + s; n < ne; n += 4) acc += h[(size_t)n*96 + d];
    ps[s][d] = acc;
  }
  __syncthreads();
  if (t < 96) pl[t] = ps[0][t] + ps[1][t] + ps[2][t] + ps[3][t];
  __syncthreads();

  if (t < 64){
    float cin[7];
    #pragma unroll
    for (int j = 0; j < 7; ++j) cin[j] = cond[g*7+j];
    float c1[5];
    #pragma unroll
    for (int i = 0; i < 5; ++i){
      float a = cb1[i];
      #pragma unroll
      for (int j = 0; j < 7; ++j) a = fmaf(cin[j], cW1[j*5+i], a);
      float sc = cg[i] * rsqrtf(cvar[i] + BN_EPS);
      a = (a - cmean[i])*sc + cbeta[i];
      c1[i] = a > 0.f ? a : 0.f;
    }
    float c2[5];
    #pragma unroll
    for (int i = 0; i < 5; ++i){
      float a = cb2[i];
      #pragma unroll
      for (int j = 0; j < 5; ++j) a = fmaf(c1[j], cW2[j*5+i], a);
      c2[i] = a > 0.f ? a : 0.f;
    }
    float acc = fcb[t];
    #pragma unroll
    for (int j = 0; j < 5; ++j){
      float sc = bn_g[j] * rsqrtf(bn_var[j] + BN_EPS);
      float nb = (c2[j] - bn_mean[j])*sc + bn_b[j];
      acc = fmaf(nb, fcW[j*64 + t], acc);
    }
    for (int j = 5; j < 101; ++j){
      float vj = pl[j-5];
      float sc = bn_g[j] * rsqrtf(bn_var[j] + BN_EPS);
      float nb = (vj - bn_mean[j])*sc + bn_b[j];
      acc = fmaf(nb, fcW[j*64 + t], acc);
    }
    out[g*64 + t] = acc;
  }
}

// ---------------- launch ----------------

extern "C" void kernel_launch(void* const* d_in, const int* in_sizes, int n_in,
                              void* d_out, int out_size, void* d_ws, size_t ws_size,
                              hipStream_t stream)
{
  const float* x         = (const float*)d_in[0];
  const float* cond      = (const float*)d_in[1];
  const int*   ei        = (const int*)  d_in[2];
  const int*   batch     = (const int*)  d_in[3];
  const float* conv_W1   = (const float*)d_in[4];
  const float* conv_b1   = (const float*)d_in[5];
  const float* conv_g    = (const float*)d_in[6];
  const float* conv_beta = (const float*)d_in[7];
  const float* conv_mean = (const float*)d_in[8];
  const float* conv_var  = (const float*)d_in[9];
  const float* conv_W2   = (const float*)d_in[10];
  const float* conv_b2   = (const float*)d_in[11];
  const float* cW1       = (const float*)d_in[12];
  const float* cb1       = (const float*)d_in[13];
  const float* cg        = (const float*)d_in[14];
  const float* cbeta     = (const float*)d_in[15];
  const float* cmean     = (const float*)d_in[16];
  const float* cvar      = (const float*)d_in[17];
  const float* cW2       = (const float*)d_in[18];
  const float* cb2       = (const float*)d_in[19];
  const float* bn_g      = (const float*)d_in[20];
  const float* bn_b      = (const float*)d_in[21];
  const float* bn_mean   = (const float*)d_in[22];
  const float* bn_var    = (const float*)d_in[23];
  const float* fc_W      = (const float*)d_in[24];
  const float* fc_b      = (const float*)d_in[25];

  const int D = 96;
  int N = in_sizes[0] / D;
  int G = in_sizes[1] / 7;
  int E = in_sizes[2] / 2;
  const int* src = ei;
  const int* dst = ei + E;

  char* p = (char*)d_ws;
  auto carve = [&](size_t bytes)->void*{
    void* r = (void*)p; p += (bytes + 255) & ~(size_t)255; return r;
  };
  int*   off    = (int*)  carve((size_t)(N+1)*4);
  int*   cursor = (int*)  carve((size_t)N*4);
  int*   bsum   = (int*)  carve(256*4);
  int*   srcs   = (int*)  carve((size_t)E*4);
  int*   go     = (int*)  carve((size_t)(G+1)*4);
  float* hA     = (float*)carve((size_t)N*D*4);
  float* hB     = (float*)carve((size_t)N*D*4);

  int gE = (E+255)/256, gN = (N+255)/256;

  hipMemsetAsync(off, 0, (size_t)(N+1)*4, stream);
  hist_k   <<<gE, 256, 0, stream>>>(dst, off, E);
  scan1_k  <<<gN, 256, 0, stream>>>(off, bsum, N);
  scan2_k  <<<1,  256, 0, stream>>>(bsum, gN);
  scan3_k  <<<gN, 256, 0, stream>>>(off, cursor, bsum, N, E);
  scatter_k<<<gE, 256, 0, stream>>>(src, dst, cursor, srcs, E);
  bounds_k <<<gN, 256, 0, stream>>>(batch, go, N, G);

  const float* hin = x;
  int nblk = (N+63)/64;
  for (int l = 0; l < 3; ++l){
    agg_k<<<(N+7)/8, 256, 0, stream>>>(hin, hB, off, srcs, N);
    mlp_sw_k<<<nblk, 256, 0, stream>>>(hB, hA,
        conv_W1 + (size_t)l*D*D, conv_b1 + l*D,
        conv_g + l*D, conv_beta + l*D, conv_mean + l*D, conv_var + l*D,
        conv_W2 + (size_t)l*D*D, conv_b2 + l*D, N);
    hin = hA;
  }

  poolfinal_k<<<G, 384, 0, stream>>>(hA, go, cond,
                                     cW1, cb1, cg, cbeta, cmean, cvar,
                                     cW2, cb2, bn_g, bn_b, bn_mean, bn_var,
                                     fc_W, fc_b, (float*)d_out);
}